// Round 3
// baseline (1532.614 us; speedup 1.0000x reference)
//
#include <hip/hip_runtime.h>
#include <limits.h>

#define NUM_Q    4096
#define MAX_STEP 256
#define BATCH    64
#define TWOQ     8192                  // 2*NUM_Q
#define ROWS     (BATCH * MAX_STEP)    // 16384
#define VEC_PER_ROW (TWOQ / 4)         // 2048 float4
#define ITERS    (VEC_PER_ROW / 64)    // 32 iters of 64 lanes x float4
#define GRID_BLOCKS (ROWS / 4)         // 4 waves (rows) per 256-thread block

__device__ __forceinline__ float bce(float p, float a) {
    // matches torch BCELoss: logs clamped at -100. logf(0)=-inf -> clamped;
    // a is exactly 0 or 1 so 0*(-100) stays finite.
    float lp  = fmaxf(logf(p), -100.0f);
    float l1p = fmaxf(log1pf(-p), -100.0f);
    return -(a * lp + (1.0f - a) * l1p);
}

// Single fused kernel.
// Phase 1: one wave per (b,s) row of batch [B,S,2Q]; early-exit ballot scan for
//          the one-hot index -> qa[row] in [0,8192) or -1 (padding).
// Phase 2: last block (threadfence-reduction pattern) computes the whole loss:
//          4 waves x 16 students, wave-shuffle reductions, out[0] written once.
__global__ void __launch_bounds__(256) fused_loss_kernel(
        const float* __restrict__ batch,
        const float* __restrict__ pred,
        const float* __restrict__ target_q,
        const float* __restrict__ target_label,
        float* __restrict__ out,
        int* __restrict__ qa,
        unsigned int* __restrict__ counter) {
    const int gtid = blockIdx.x * 256 + threadIdx.x;
    const int row  = gtid >> 6;        // global wave id = row, exactly ROWS waves
    const int lane = gtid & 63;

    // ---------------- Phase 1: one-hot scan ----------------
    {
        const float4* rp = (const float4*)(batch + (size_t)row * TWOQ);
        int found = -1;
        float4 v = rp[lane];                                    // iter 0 in flight
        for (int it = 0; it < ITERS; ++it) {
            float4 nv;
            if (it + 1 < ITERS) nv = rp[(it + 1) * 64 + lane];  // prefetch 1KB
            const float s = v.x + v.y + v.z + v.w;              // 0.0 or 1.0
            const unsigned long long m = __ballot(s > 0.0f);    // wave-uniform
            if (m) {
                const int src = __ffsll(m) - 1;
                int idx = 0;
                if (lane == src) {
                    const int base = (it * 64 + lane) * 4;
                    idx = (v.x != 0.f) ? base
                        : (v.y != 0.f) ? base + 1
                        : (v.z != 0.f) ? base + 2
                                       : base + 3;
                }
                found = __shfl(idx, src);
                break;
            }
            v = nv;
        }
        if (lane == 0) qa[row] = found;
    }

    // ---------------- last-block election ----------------
    __shared__ int isLast;
    __threadfence();                    // publish qa writes device-wide
    __syncthreads();                    // all 4 waves of this block done
    if (threadIdx.x == 0) {
        unsigned int old = atomicAdd(counter, 1u);
        isLast = (old == GRID_BLOCKS - 1u);
    }
    __syncthreads();
    if (!isLast) return;
    __threadfence();                    // acquire: see all blocks' qa writes

    // ---------------- Phase 2: loss (one block) ----------------
    const int w = threadIdx.x >> 6;     // wave 0..3
    __shared__ float wacc[4];
    float acc = 0.0f;

    for (int j = 0; j < 16; ++j) {
        const int b = w * 16 + j;
        // lane covers steps t = lane, lane+64, lane+128, lane+192 (t < 255)
        int   cand = INT_MAX;
        float pv[4], av[4];
        #pragma unroll
        for (int k = 0; k < 4; ++k) {
            const int t = lane + 64 * k;
            pv[k] = 0.0f; av[k] = 0.0f;
            if (t < MAX_STEP - 1) {
                const int idx = qa[b * MAX_STEP + t + 1];
                if (idx >= 0) {
                    const int qid = idx & (NUM_Q - 1);
                    pv[k] = pred[((size_t)b * MAX_STEP + t) * NUM_Q + qid];
                    av[k] = (idx < NUM_Q) ? 1.0f : 0.0f;
                    cand = min(cand, t);        // pred>=0.01 so valid => p>0
                }
            }
        }
        // wave min-reduce for trim index i
        #pragma unroll
        for (int off = 32; off > 0; off >>= 1)
            cand = min(cand, __shfl_down(cand, off));
        int i0 = __shfl(cand, 0);
        if (i0 == INT_MAX) i0 = 0;              // argmax of all-false -> 0

        // masked BCE sum
        float s = 0.0f;
        #pragma unroll
        for (int k = 0; k < 4; ++k) {
            const int t = lane + 64 * k;
            if (t < MAX_STEP - 1 && t >= i0) s += bce(pv[k], av[k]);
        }
        #pragma unroll
        for (int off = 32; off > 0; off >>= 1)
            s += __shfl_down(s, off);

        if (lane == 0) {
            const float tail = bce(target_q[b], target_label[b]);
            const float n = (float)(MAX_STEP - i0);  // (S-1) - i + 1
            acc += (s + tail) / n;
        }
    }

    if (lane == 0) wacc[w] = acc;
    __syncthreads();
    if (threadIdx.x == 0)
        out[0] = wacc[0] + wacc[1] + wacc[2] + wacc[3];
}

extern "C" void kernel_launch(void* const* d_in, const int* in_sizes, int n_in,
                              void* d_out, int out_size, void* d_ws, size_t ws_size,
                              hipStream_t stream) {
    const float* pred         = (const float*)d_in[0];  // [B,S,Q]
    const float* target_q     = (const float*)d_in[1];  // [B,1]
    const float* batch        = (const float*)d_in[2];  // [B,S,2Q]
    const float* target_label = (const float*)d_in[3];  // [B]
    float* out = (float*)d_out;

    unsigned int* counter = (unsigned int*)d_ws;         // 4 B, must be zeroed
    int* qa = (int*)d_ws + 64;                           // ROWS ints, 256B-aligned off

    hipMemsetAsync(counter, 0, sizeof(unsigned int), stream);
    fused_loss_kernel<<<GRID_BLOCKS, 256, 0, stream>>>(
        batch, pred, target_q, target_label, out, qa, counter);
}

// Round 4
// 796.221 us; speedup vs baseline: 1.9249x; 1.9249x over previous
//
#include <hip/hip_runtime.h>
#include <limits.h>

#define NUM_Q    4096
#define MAX_STEP 256
#define BATCH    64
#define TWOQ     8192                  // 2*NUM_Q
#define ROWS     (BATCH * MAX_STEP)    // 16384
#define VEC_PER_ROW (TWOQ / 4)         // 2048 float4
#define ITERS    (VEC_PER_ROW / 64)    // 32 iters of 64 lanes x float4

// Kernel 1: ONE WAVE per (b,s) row of batch [B,S,2Q]. Early-exit ballot scan
// for the single one-hot index; values are exactly 0.0/1.0. qa[row] = idx in
// [0,8192) or -1 (padding row). Expected read ~45% of row (hot position is
// uniform per half, 0.6/0.4 split) -> ~230 MB expected vs 512 MB full scan.
// NOTE (R3 lesson): do NOT fuse the consumer behind a last-block election —
// agent-scope __threadfence per block costs ~µs each on gfx950 (L2 writeback,
// non-coherent per-XCD L2s); 4096 blocks made it 920 µs. Kernel boundary is free.
__global__ void __launch_bounds__(256) find_onehot_kernel(
        const float* __restrict__ batch, int* __restrict__ qa) {
    const int gtid = blockIdx.x * 256 + threadIdx.x;
    const int row  = gtid >> 6;        // global wave id = row; grid covers exactly
    const int lane = gtid & 63;

    const float4* rp = (const float4*)(batch + (size_t)row * TWOQ);

    int found = -1;
    float4 v = rp[lane];               // iter 0 in flight
    for (int it = 0; it < ITERS; ++it) {
        float4 nv;
        if (it + 1 < ITERS) nv = rp[(it + 1) * 64 + lane];  // prefetch next 1KB
        const float s = v.x + v.y + v.z + v.w;              // 0.0 or 1.0
        const unsigned long long m = __ballot(s > 0.0f);    // wave-uniform
        if (m) {
            const int src = __ffsll(m) - 1;
            int idx = 0;
            if (lane == src) {
                const int base = (it * 64 + lane) * 4;
                idx = (v.x != 0.f) ? base
                    : (v.y != 0.f) ? base + 1
                    : (v.z != 0.f) ? base + 2
                                   : base + 3;
            }
            found = __shfl(idx, src);
            break;
        }
        v = nv;
    }
    if (lane == 0) qa[row] = found;
}

__device__ __forceinline__ float bce(float p, float a) {
    // matches torch BCELoss: logs clamped at -100. logf(0)=-inf -> clamped;
    // a is exactly 0 or 1 so products stay finite.
    float lp  = fmaxf(logf(p), -100.0f);
    float l1p = fmaxf(log1pf(-p), -100.0f);
    return -(a * lp + (1.0f - a) * l1p);
}

// Kernel 2: ONE block, 4 waves x 16 students each. Wave-shuffle reductions,
// no LDS trees, no atomics; out[0] written once (no memset dispatch needed).
__global__ void __launch_bounds__(256) loss_kernel(
        const float* __restrict__ pred,
        const float* __restrict__ target_q,
        const float* __restrict__ target_label,
        const int* __restrict__ qa,
        float* __restrict__ out) {
    const int w    = threadIdx.x >> 6;   // wave 0..3
    const int lane = threadIdx.x & 63;
    __shared__ float wacc[4];
    float acc = 0.0f;

    for (int j = 0; j < 16; ++j) {
        const int b = w * 16 + j;
        // lane covers steps t = lane, lane+64, lane+128, lane+192 (t < 255)
        int   cand = INT_MAX;
        float pv[4], av[4];
        #pragma unroll
        for (int k = 0; k < 4; ++k) {
            const int t = lane + 64 * k;
            pv[k] = 0.0f; av[k] = 0.0f;
            if (t < MAX_STEP - 1) {
                const int idx = qa[b * MAX_STEP + t + 1];
                if (idx >= 0) {
                    const int qid = idx & (NUM_Q - 1);
                    pv[k] = pred[((size_t)b * MAX_STEP + t) * NUM_Q + qid];
                    av[k] = (idx < NUM_Q) ? 1.0f : 0.0f;
                    cand = min(cand, t);        // pred>=0.01 so valid => p>0
                }
            }
        }
        // wave min-reduce for trim index i
        #pragma unroll
        for (int off = 32; off > 0; off >>= 1)
            cand = min(cand, __shfl_down(cand, off));
        int i0 = __shfl(cand, 0);
        if (i0 == INT_MAX) i0 = 0;              // argmax of all-false -> 0

        // masked BCE sum over t >= i0
        float s = 0.0f;
        #pragma unroll
        for (int k = 0; k < 4; ++k) {
            const int t = lane + 64 * k;
            if (t < MAX_STEP - 1 && t >= i0) s += bce(pv[k], av[k]);
        }
        #pragma unroll
        for (int off = 32; off > 0; off >>= 1)
            s += __shfl_down(s, off);

        if (lane == 0) {
            const float tail = bce(target_q[b], target_label[b]);
            const float n = (float)(MAX_STEP - i0);  // (S-1) - i + 1
            acc += (s + tail) / n;
        }
    }

    if (lane == 0) wacc[w] = acc;
    __syncthreads();
    if (threadIdx.x == 0)
        out[0] = wacc[0] + wacc[1] + wacc[2] + wacc[3];
}

extern "C" void kernel_launch(void* const* d_in, const int* in_sizes, int n_in,
                              void* d_out, int out_size, void* d_ws, size_t ws_size,
                              hipStream_t stream) {
    const float* pred         = (const float*)d_in[0];  // [B,S,Q]
    const float* target_q     = (const float*)d_in[1];  // [B,1]
    const float* batch        = (const float*)d_in[2];  // [B,S,2Q]
    const float* target_label = (const float*)d_in[3];  // [B]
    float* out = (float*)d_out;
    int*   qa  = (int*)d_ws;   // ROWS ints = 64 KB

    // one wave per row: ROWS waves, 256-thread blocks -> 4096 blocks
    find_onehot_kernel<<<(ROWS * 64) / 256, 256, 0, stream>>>(batch, qa);
    loss_kernel<<<1, 256, 0, stream>>>(pred, target_q, target_label, qa, out);
}

// Round 5
// 772.357 us; speedup vs baseline: 1.9843x; 1.0309x over previous
//
#include <hip/hip_runtime.h>
#include <limits.h>

#define NUM_Q    4096
#define MAX_STEP 256
#define BATCH    64
#define TWOQ     8192                  // 2*NUM_Q
#define ROWS     (BATCH * MAX_STEP)    // 16384
#define VEC_PER_ROW (TWOQ / 4)         // 2048 float4
#define ITERS    (VEC_PER_ROW / 64)    // 32 iters of 64 lanes x float4

// Kernel 1: ONE WAVE per (b,s) row of batch [B,S,2Q]. Early-exit ballot scan
// for the single one-hot index; values are exactly 0.0/1.0. qa[row] = idx in
// [0,8192) or -1 (padding row). Expected read ~45% of row (hot position is
// uniform per half, 0.6/0.4 split) -> ~230 MB expected vs 512 MB full scan;
// sequential order is the optimal static probe order, so this is the floor.
// NOTE (R3 lesson): do NOT fuse the consumer behind a last-block election —
// agent-scope __threadfence per block costs ~225 ns each on gfx950 (L2
// writeback, non-coherent per-XCD L2s); 4096 blocks made it 920 µs.
__global__ void __launch_bounds__(256) find_onehot_kernel(
        const float* __restrict__ batch, int* __restrict__ qa) {
    const int gtid = blockIdx.x * 256 + threadIdx.x;
    const int row  = gtid >> 6;        // global wave id = row; grid covers exactly
    const int lane = gtid & 63;

    // qa[b][0] is never consumed (loss reads qa[b][t+1], t>=0): skip the scan.
    if ((row & (MAX_STEP - 1)) == 0) {
        if (lane == 0) qa[row] = -1;
        return;
    }

    const float4* rp = (const float4*)(batch + (size_t)row * TWOQ);

    int found = -1;
    float4 v = rp[lane];               // iter 0 in flight
    for (int it = 0; it < ITERS; ++it) {
        float4 nv;
        if (it + 1 < ITERS) nv = rp[(it + 1) * 64 + lane];  // prefetch next 1KB
        const float s = v.x + v.y + v.z + v.w;              // 0.0 or 1.0
        const unsigned long long m = __ballot(s > 0.0f);    // wave-uniform
        if (m) {
            const int src = __ffsll(m) - 1;
            int idx = 0;
            if (lane == src) {
                const int base = (it * 64 + lane) * 4;
                idx = (v.x != 0.f) ? base
                    : (v.y != 0.f) ? base + 1
                    : (v.z != 0.f) ? base + 2
                                   : base + 3;
            }
            found = __shfl(idx, src);
            break;
        }
        v = nv;
    }
    if (lane == 0) qa[row] = found;
}

__device__ __forceinline__ float bce(float p, float a) {
    // matches torch BCELoss: logs clamped at -100. logf(0)=-inf -> clamped;
    // a is exactly 0 or 1 so products stay finite.
    float lp  = fmaxf(logf(p), -100.0f);
    float l1p = fmaxf(log1pf(-p), -100.0f);
    return -(a * lp + (1.0f - a) * l1p);
}

// Kernel 2: ONE block, 16 waves (1024 threads); each wave owns 4 students.
// All qa loads issued first, then all pred gathers (two latency epochs, fully
// overlapped MLP) — R4's 4-wave version serialized 16 dependent chains/wave.
// No atomics, no memset: out[0] written once by thread 0.
__global__ void __launch_bounds__(1024) loss_kernel(
        const float* __restrict__ pred,
        const float* __restrict__ target_q,
        const float* __restrict__ target_label,
        const int* __restrict__ qa,
        float* __restrict__ out) {
    const int w    = threadIdx.x >> 6;   // wave 0..15
    const int lane = threadIdx.x & 63;
    __shared__ float wacc[16];

    // ---- epoch 1: all qa loads for this wave's 4 students ----
    int idxv[4][4];                      // [student j][stride k]
    #pragma unroll
    for (int j = 0; j < 4; ++j) {
        const int b = w * 4 + j;
        #pragma unroll
        for (int k = 0; k < 4; ++k) {
            const int t = lane + 64 * k;
            idxv[j][k] = (t < MAX_STEP - 1) ? qa[b * MAX_STEP + t + 1] : -1;
        }
    }

    // ---- epoch 2: all pred gathers ----
    float pv[4][4];
    #pragma unroll
    for (int j = 0; j < 4; ++j) {
        const int b = w * 4 + j;
        #pragma unroll
        for (int k = 0; k < 4; ++k) {
            const int t = lane + 64 * k;
            const int idx = idxv[j][k];
            pv[j][k] = (idx >= 0)
                ? pred[((size_t)b * MAX_STEP + t) * NUM_Q + (idx & (NUM_Q - 1))]
                : 0.0f;
        }
    }

    // ---- per-student reductions ----
    float acc = 0.0f;
    #pragma unroll
    for (int j = 0; j < 4; ++j) {
        const int b = w * 4 + j;

        int cand = INT_MAX;
        #pragma unroll
        for (int k = 0; k < 4; ++k) {
            const int t = lane + 64 * k;
            if (idxv[j][k] >= 0) cand = min(cand, t);  // pred>=0.01 => p>0
        }
        #pragma unroll
        for (int off = 32; off > 0; off >>= 1)
            cand = min(cand, __shfl_down(cand, off));
        int i0 = __shfl(cand, 0);
        if (i0 == INT_MAX) i0 = 0;                     // argmax all-false -> 0

        float s = 0.0f;
        #pragma unroll
        for (int k = 0; k < 4; ++k) {
            const int t = lane + 64 * k;
            if (t < MAX_STEP - 1 && t >= i0) {
                const float a = (idxv[j][k] >= 0 && idxv[j][k] < NUM_Q) ? 1.0f : 0.0f;
                s += bce(pv[j][k], a);
            }
        }
        #pragma unroll
        for (int off = 32; off > 0; off >>= 1)
            s += __shfl_down(s, off);

        if (lane == 0) {
            const float tail = bce(target_q[b], target_label[b]);
            const float n = (float)(MAX_STEP - i0);    // (S-1) - i + 1
            acc += (s + tail) / n;
        }
    }

    if (lane == 0) wacc[w] = acc;
    __syncthreads();
    if (threadIdx.x == 0) {
        float r = 0.0f;
        #pragma unroll
        for (int w2 = 0; w2 < 16; ++w2) r += wacc[w2];
        out[0] = r;
    }
}

extern "C" void kernel_launch(void* const* d_in, const int* in_sizes, int n_in,
                              void* d_out, int out_size, void* d_ws, size_t ws_size,
                              hipStream_t stream) {
    const float* pred         = (const float*)d_in[0];  // [B,S,Q]
    const float* target_q     = (const float*)d_in[1];  // [B,1]
    const float* batch        = (const float*)d_in[2];  // [B,S,2Q]
    const float* target_label = (const float*)d_in[3];  // [B]
    float* out = (float*)d_out;
    int*   qa  = (int*)d_ws;   // ROWS ints = 64 KB

    // one wave per row: ROWS waves, 256-thread blocks -> 4096 blocks
    find_onehot_kernel<<<(ROWS * 64) / 256, 256, 0, stream>>>(batch, qa);
    loss_kernel<<<1, 1024, 0, stream>>>(pred, target_q, target_label, qa, out);
}